// Round 2
// baseline (47854.718 us; speedup 1.0000x reference)
//
#include <hip/hip_runtime.h>
#include <hip/hip_cooperative_groups.h>

namespace cg = cooperative_groups;

constexpr int B = 128, T = 512, D = 256, U = 512, OUTD = 64;
constexpr int NG = 4 * U;            // 2048 gate columns
constexpr int KTOT = D + U;          // 768
constexpr int NWG = 256;             // workgroups (1 per CU)
constexpr int NTH = 256;             // threads per wg
constexpr int GB = 4;                // batch groups
constexpr int BPG = B / GB;          // 32 batches per group
constexpr int CGN = NWG / GB;        // 64 unit groups (also = OUTD)
constexpr int UPW = U / CGN;         // 8 units per wg
constexpr int VROW = 772;            // padded LDS row (floats): 768 + 4
constexpr int VROW4 = VROW / 4;      // 193

// ws layout (floats)
constexpr size_t WR_OFF = 0;
constexpr size_t WR_SZ = (size_t)KTOT * NG;   // 1,572,864 (6 MB)
constexpr size_t BIASR_OFF = WR_OFF + WR_SZ;
constexpr size_t BIASR_SZ = 2 * NG;
constexpr size_t DWT_OFF = BIASR_OFF + BIASR_SZ;
constexpr size_t DWT_SZ = (size_t)OUTD * U;
constexpr size_t H_OFF = DWT_OFF + DWT_SZ;
constexpr size_t H_SZ = (size_t)B * U;        // 65,536
// total ~1.74M floats ~ 7 MB

__device__ __forceinline__ float sigmoidf_(float z) {
    return 1.f / (1.f + __expf(-z));
}
__device__ __forceinline__ float tanhf_(float z) {
    // stable for |z| large: exp->inf gives 1, exp->0 gives -1
    return 1.f - 2.f / (1.f + __expf(2.f * z));
}

// Build Wr[k][u*4+g] for k in [0,768):
//   k < D:        kernel[k][g*512+u]
//   k >= D (kh):  rec_kernel[kh][g*512+u] + sum_o dense_w[kh][o]*kernel[D+o][g*512+u]
__global__ void prep_wr(const float* __restrict__ kernelW,
                        const float* __restrict__ recW,
                        const float* __restrict__ denseW,
                        float* __restrict__ Wr) {
    int idx = blockIdx.x * blockDim.x + threadIdx.x;  // [0, 768*2048)
    int k = idx >> 11;
    int c = idx & (NG - 1);
    int u = c >> 2, g = c & 3;
    int col = g * U + u;
    float w;
    if (k < D) {
        w = kernelW[(size_t)k * NG + col];
    } else {
        int kh = k - D;
        w = recW[(size_t)kh * NG + col];
        float acc = 0.f;
#pragma unroll 8
        for (int o = 0; o < OUTD; ++o)
            acc = fmaf(denseW[kh * OUTD + o], kernelW[(size_t)(D + o) * NG + col], acc);
        w += acc;
    }
    Wr[idx] = w;
}

// biasr[0][c] = bias (t==0), biasr[1][c] = bias + dense_b @ Wtag (t>0); dwT[o][u] = dense_w[u][o]
__global__ void prep_misc(const float* __restrict__ kernelW,
                          const float* __restrict__ bias,
                          const float* __restrict__ denseW,
                          const float* __restrict__ denseB,
                          float* __restrict__ biasr,
                          float* __restrict__ dwT) {
    int idx = blockIdx.x * blockDim.x + threadIdx.x;  // [0, 64*512)
    if (idx < NG) {
        int u = idx >> 2, g = idx & 3;
        int col = g * U + u;
        float b0 = bias[col];
        float corr = 0.f;
        for (int o = 0; o < OUTD; ++o)
            corr = fmaf(denseB[o], kernelW[(size_t)(D + o) * NG + col], corr);
        biasr[idx] = b0;
        biasr[NG + idx] = b0 + corr;
    }
    if (idx < OUTD * U) {
        int o = idx >> 9, u = idx & (U - 1);
        dwT[idx] = denseW[u * OUTD + o];
    }
}

__global__ __launch_bounds__(NTH)
void lstm_seq(const float* __restrict__ x,
              const float* __restrict__ Wr,
              const float* __restrict__ biasr,
              const float* __restrict__ dwT,
              const float* __restrict__ denseB,
              float* __restrict__ h0,
              float* __restrict__ h1,
              float* __restrict__ out) {
    extern __shared__ float smem[];
    float* v = smem;                    // [32][VROW]  ([x_t | h_t] per batch row)
    float* ybuf = smem + BPG * VROW;    // [32][8] partial y sums

    cg::grid_group grid = cg::this_grid();

    const int w = blockIdx.x;
    const int gb = w & (GB - 1);        // batch group 0..3
    const int cgp = w >> 2;             // unit/output group 0..63
    const int tid = threadIdx.x;
    const int uloc = tid & (UPW - 1);   // 0..7
    const int bloc = tid >> 3;          // 0..31
    const int u = cgp * UPW + uloc;     // 0..511
    const int b = gb * BPG + bloc;      // 0..127

    const float4* Wr4 = (const float4*)Wr;       // [768][512] float4 rows
    const float4* x4 = (const float4*)x;
    const float4* biasr4 = (const float4*)biasr;

    // zero h0 (grid exactly covers H_SZ elements)
    h0[w * NTH + tid] = 0.f;
    grid.sync();

    float cstate = 0.f;
    float* hc = h0;   // h_t
    float* hn = h1;   // h_{t+1}

    for (int t = 0; t <= T; ++t) {
        const int ts = (t < T) ? t : (T - 1);
        // ---- stage v = [x[:,ts,:], h_t] for this wg's 32 batch rows ----
        {
            const float4* h4 = (const float4*)hc;
            float4* v4 = (float4*)v;
#pragma unroll
            for (int i = 0; i < 24; ++i) {
                int idx = i * NTH + tid;          // [0, 32*192)
                int r = idx / 192;
                int cc = idx - r * 192;
                float4 val;
                if (cc < 64)
                    val = x4[(size_t)(gb * BPG + r) * (T * 64) + (size_t)ts * 64 + cc];
                else
                    val = h4[(gb * BPG + r) * 128 + (cc - 64)];
                v4[r * VROW4 + cc] = val;
            }
        }
        __syncthreads();

        // ---- y for step t-1 (uses h_t staged in LDS), output column = cgp ----
        if (t > 0) {
            const float* hrow = v + bloc * VROW + D;
            const float* dwrow = dwT + cgp * U + uloc * 64;
            float partial = 0.f;
#pragma unroll 8
            for (int j = 0; j < 64; ++j)
                partial = fmaf(hrow[uloc * 64 + j], dwrow[j], partial);
            ybuf[bloc * 8 + uloc] = partial;
        }

        // ---- main gate GEMM: 4 dots of length 768 per thread ----
        float4 acc = make_float4(0.f, 0.f, 0.f, 0.f);
        if (t < T) {
            acc = biasr4[(t > 0 ? 512 : 0) + u];
            const float4* vrow4 = (const float4*)(v + bloc * VROW);
            const float4* wp = Wr4 + u;
#pragma unroll 8
            for (int k4 = 0; k4 < 192; ++k4) {
                float4 vv = vrow4[k4];
                float4 w0 = wp[0];
                float4 w1 = wp[512];
                float4 w2 = wp[1024];
                float4 w3 = wp[1536];
                wp += 2048;
                acc.x = fmaf(vv.x, w0.x, acc.x);
                acc.y = fmaf(vv.x, w0.y, acc.y);
                acc.z = fmaf(vv.x, w0.z, acc.z);
                acc.w = fmaf(vv.x, w0.w, acc.w);
                acc.x = fmaf(vv.y, w1.x, acc.x);
                acc.y = fmaf(vv.y, w1.y, acc.y);
                acc.z = fmaf(vv.y, w1.z, acc.z);
                acc.w = fmaf(vv.y, w1.w, acc.w);
                acc.x = fmaf(vv.z, w2.x, acc.x);
                acc.y = fmaf(vv.z, w2.y, acc.y);
                acc.z = fmaf(vv.z, w2.z, acc.z);
                acc.w = fmaf(vv.z, w2.w, acc.w);
                acc.x = fmaf(vv.w, w3.x, acc.x);
                acc.y = fmaf(vv.w, w3.y, acc.y);
                acc.z = fmaf(vv.w, w3.z, acc.z);
                acc.w = fmaf(vv.w, w3.w, acc.w);
            }
        }
        __syncthreads();  // ybuf complete

        if (t > 0 && uloc == 0) {
            float yv = denseB[cgp];
#pragma unroll
            for (int q = 0; q < 8; ++q) yv += ybuf[bloc * 8 + q];
            out[(size_t)b * (T * OUTD) + (size_t)(t - 1) * OUTD + cgp] = yv;
        }

        if (t < T) {
            float ig = sigmoidf_(acc.x);
            float fg = sigmoidf_(acc.y);
            float gg = tanhf_(acc.z);
            float og = sigmoidf_(acc.w);
            cstate = fmaf(fg, cstate, ig * gg);
            float hnew = og * tanhf_(cstate);
            hn[b * U + u] = hnew;
            __threadfence();
            grid.sync();
            float* tmp = hc; hc = hn; hn = tmp;
        }
    }
}

extern "C" void kernel_launch(void* const* d_in, const int* in_sizes, int n_in,
                              void* d_out, int out_size, void* d_ws, size_t ws_size,
                              hipStream_t stream) {
    const float* x = (const float*)d_in[0];
    const float* kernelW = (const float*)d_in[1];
    const float* recW = (const float*)d_in[2];
    const float* bias = (const float*)d_in[3];
    const float* denseW = (const float*)d_in[4];
    const float* denseB = (const float*)d_in[5];
    float* ws = (float*)d_ws;
    float* Wr = ws + WR_OFF;
    float* biasr = ws + BIASR_OFF;
    float* dwT = ws + DWT_OFF;
    float* h0 = ws + H_OFF;
    float* h1 = ws + H_OFF + H_SZ;
    float* out = (float*)d_out;

    prep_wr<<<(KTOT * NG) / 256, 256, 0, stream>>>(kernelW, recW, denseW, Wr);
    prep_misc<<<(OUTD * U) / 256, 256, 0, stream>>>(kernelW, bias, denseW, denseB, biasr, dwT);

    size_t smem = (size_t)(BPG * VROW + BPG * 8) * sizeof(float);  // ~99.8 KB
    hipFuncSetAttribute(reinterpret_cast<const void*>(lstm_seq),
                        hipFuncAttributeMaxDynamicSharedMemorySize, (int)smem);

    void* args[] = {(void*)&x, (void*)&Wr, (void*)&biasr, (void*)&dwT, (void*)&denseB,
                    (void*)&h0, (void*)&h1, (void*)&out};
    hipLaunchCooperativeKernel(reinterpret_cast<void*>(lstm_seq),
                               dim3(NWG), dim3(NTH), args, (unsigned)smem, stream);
}

// Round 3
// 17103.815 us; speedup vs baseline: 2.7979x; 2.7979x over previous
//
#include <hip/hip_runtime.h>

using f32x4 = __attribute__((ext_vector_type(4))) float;

constexpr int B = 128, T = 512, D = 256, U = 512, OUTD = 64;
constexpr int NG = 4 * U;            // 2048 gate columns
constexpr int KTOT = D + U;          // 768
constexpr int NWG = 256;             // workgroups (1 per CU)
constexpr int NTH = 256;             // threads per wg
constexpr int GB = 4;                // batch groups
constexpr int BPG = B / GB;          // 32 batches per group
constexpr int CGN = NWG / GB;        // 64 unit groups (= OUTD)
constexpr int UPW = U / CGN;         // 8 units per wg
constexpr int VROW = 772;            // padded LDS row (floats): 768 + 4
constexpr int VROW4 = VROW / 4;      // 193

// ws layout (floats)
constexpr size_t WR_OFF = 0;
constexpr size_t WR_SZ = (size_t)KTOT * NG;       // 6 MB
constexpr size_t BIASR_OFF = WR_OFF + WR_SZ;
constexpr size_t BIASR_SZ = 2 * NG;
constexpr size_t DWT_OFF = BIASR_OFF + BIASR_SZ;
constexpr size_t DWT_SZ = (size_t)OUTD * U;
constexpr size_t H_OFF = DWT_OFF + DWT_SZ;
constexpr size_t H_SZ = (size_t)B * U;            // 65,536 floats per buffer
constexpr size_t SYNC_OFF = H_OFF + 2 * H_SZ;     // 1024 unsigned words
constexpr unsigned GCTR_STRIDE = 64;              // ints between group counters
constexpr unsigned ROOT_IDX = 576;
constexpr unsigned GEN_IDX = 640;

__device__ __forceinline__ float sigmoidf_(float z) { return 1.f / (1.f + __expf(-z)); }
__device__ __forceinline__ float tanhf_(float z) { return 1.f - 2.f / (1.f + __expf(2.f * z)); }

// ---------------- prep kernels ----------------
__global__ void prep_wr(const float* __restrict__ kernelW,
                        const float* __restrict__ recW,
                        const float* __restrict__ denseW,
                        float* __restrict__ Wr) {
    int idx = blockIdx.x * blockDim.x + threadIdx.x;  // [0, 768*2048)
    int k = idx >> 11;
    int c = idx & (NG - 1);
    int u = c >> 2, g = c & 3;
    int col = g * U + u;
    float w;
    if (k < D) {
        w = kernelW[(size_t)k * NG + col];
    } else {
        int kh = k - D;
        w = recW[(size_t)kh * NG + col];
        float acc = 0.f;
#pragma unroll 8
        for (int o = 0; o < OUTD; ++o)
            acc = fmaf(denseW[kh * OUTD + o], kernelW[(size_t)(D + o) * NG + col], acc);
        w += acc;
    }
    Wr[idx] = w;
}

__global__ void prep_misc(const float* __restrict__ kernelW,
                          const float* __restrict__ bias,
                          const float* __restrict__ denseW,
                          const float* __restrict__ denseB,
                          float* __restrict__ biasr,
                          float* __restrict__ dwT) {
    int idx = blockIdx.x * blockDim.x + threadIdx.x;  // [0, 64*512)
    if (idx < NG) {
        int u = idx >> 2, g = idx & 3;
        int col = g * U + u;
        float b0 = bias[col];
        float corr = 0.f;
        for (int o = 0; o < OUTD; ++o)
            corr = fmaf(denseB[o], kernelW[(size_t)(D + o) * NG + col], corr);
        biasr[idx] = b0;
        biasr[NG + idx] = b0 + corr;
    }
    if (idx < OUTD * U) {
        int o = idx >> 9, u = idx & (U - 1);
        dwT[idx] = denseW[u * OUTD + o];
    }
}

__global__ void prep_zero(float* __restrict__ hbufs, unsigned* __restrict__ sync) {
    int idx = blockIdx.x * blockDim.x + threadIdx.x;   // 512*256 = 131072 = 2*H_SZ
    hbufs[idx] = 0.f;
    if (idx < 1024)
        __hip_atomic_store(&sync[idx], 0u, __ATOMIC_RELAXED, __HIP_MEMORY_SCOPE_AGENT);
}

// ---------------- barrier ----------------
__device__ __forceinline__ void barrier_arrive(unsigned* sync, int w, unsigned t) {
    unsigned g = (unsigned)w >> 5;  // 8 groups of 32 wgs
    unsigned old = __hip_atomic_fetch_add(&sync[g * GCTR_STRIDE], 1u,
                                          __ATOMIC_RELAXED, __HIP_MEMORY_SCOPE_AGENT);
    if (old == 32u * (t + 1u) - 1u) {
        unsigned r = __hip_atomic_fetch_add(&sync[ROOT_IDX], 1u,
                                            __ATOMIC_RELAXED, __HIP_MEMORY_SCOPE_AGENT);
        if (r == 8u * (t + 1u) - 1u)
            __hip_atomic_store(&sync[GEN_IDX], t + 1u,
                               __ATOMIC_RELAXED, __HIP_MEMORY_SCOPE_AGENT);
    }
}
__device__ __forceinline__ void barrier_wait(unsigned* sync, unsigned t) {
    while (__hip_atomic_load(&sync[GEN_IDX], __ATOMIC_RELAXED,
                             __HIP_MEMORY_SCOPE_AGENT) < t + 1u)
        __builtin_amdgcn_s_sleep(1);
}

// K-range GEMM: acc[g] += sum_k v[k] * W[k][u*4+g], N4 float4-k-groups
template <int N4>
__device__ __forceinline__ void gemm_range(f32x4& acc, const f32x4* vrow, const f32x4* wp) {
#pragma unroll 8
    for (int k4 = 0; k4 < N4; ++k4) {
        f32x4 vv = vrow[k4];
        f32x4 w0 = wp[0];
        f32x4 w1 = wp[512];
        f32x4 w2 = wp[1024];
        f32x4 w3 = wp[1536];
        wp += 2048;
        acc.x = fmaf(vv.x, w0.x, acc.x);
        acc.y = fmaf(vv.x, w0.y, acc.y);
        acc.z = fmaf(vv.x, w0.z, acc.z);
        acc.w = fmaf(vv.x, w0.w, acc.w);
        acc.x = fmaf(vv.y, w1.x, acc.x);
        acc.y = fmaf(vv.y, w1.y, acc.y);
        acc.z = fmaf(vv.y, w1.z, acc.z);
        acc.w = fmaf(vv.y, w1.w, acc.w);
        acc.x = fmaf(vv.z, w2.x, acc.x);
        acc.y = fmaf(vv.z, w2.y, acc.y);
        acc.z = fmaf(vv.z, w2.z, acc.z);
        acc.w = fmaf(vv.z, w2.w, acc.w);
        acc.x = fmaf(vv.w, w3.x, acc.x);
        acc.y = fmaf(vv.w, w3.y, acc.y);
        acc.z = fmaf(vv.w, w3.z, acc.z);
        acc.w = fmaf(vv.w, w3.w, acc.w);
    }
}

// ---------------- main persistent kernel ----------------
__global__ __launch_bounds__(NTH)
void lstm_seq(const float* __restrict__ x,
              const float* __restrict__ Wr,
              const float* __restrict__ biasr,
              const float* __restrict__ dwT,
              const float* __restrict__ denseB,
              float* __restrict__ h0,
              float* __restrict__ h1,
              float* __restrict__ out,
              unsigned* __restrict__ sync) {
    extern __shared__ float smem[];
    float* v = smem;                    // [32][VROW]: cols [0,256)=x_t, [256,768)=h_t
    float* ybuf = smem + BPG * VROW;    // [32][8]

    const int w = blockIdx.x;
    const int gb = w & (GB - 1);
    const int cgp = w >> 2;
    const int tid = threadIdx.x;
    const int uloc = tid & (UPW - 1);
    const int bloc = tid >> 3;
    const int u = cgp * UPW + uloc;
    const int b = gb * BPG + bloc;

    const f32x4* Wr4 = (const f32x4*)Wr;
    const f32x4* x4 = (const f32x4*)x;
    const f32x4* biasr4 = (const f32x4*)biasr;
    f32x4* v4 = (f32x4*)v;
    const f32x4* vrow4 = (const f32x4*)(v + bloc * VROW);

    // ---- pre-loop: stage x[0], compute xacc_0 (with t==0 bias) ----
#pragma unroll
    for (int i = 0; i < 8; ++i) {
        int idx = i * NTH + tid;          // [0, 2048)
        int r = idx >> 6, c = idx & 63;
        v4[r * VROW4 + c] = x4[(size_t)(gb * BPG + r) * (T * 64) + c];  // t=0
    }
    __syncthreads();
    f32x4 xacc = biasr4[u];
    gemm_range<64>(xacc, vrow4, Wr4 + u);

    float cstate = 0.f;

    for (int t = 0; t < T; ++t) {
        // ---- gates for step t: xacc (+ h-part if t>0) ----
        f32x4 gate = xacc;
        if (t > 0)
            gemm_range<128>(gate, vrow4 + 64, Wr4 + (size_t)64 * 2048 + u);

        float ig = sigmoidf_(gate.x);
        float fg = sigmoidf_(gate.y);
        float gg = tanhf_(gate.z);
        float og = sigmoidf_(gate.w);
        cstate = fmaf(fg, cstate, ig * gg);
        float hnew = og * tanhf_(cstate);

        float* hnb = ((t + 1) & 1) ? h1 : h0;     // slot for h_{t+1}
        __hip_atomic_store(&hnb[b * U + u], hnew, __ATOMIC_RELAXED, __HIP_MEMORY_SCOPE_AGENT);

        __syncthreads();   // #1: v reads of step t done; sc1 h stores drained
        if (tid == 0) barrier_arrive(sync, w, (unsigned)t);

        // ---- hidden work while other wgs arrive ----
        if (t + 1 < T) {  // stage x[t+1]
#pragma unroll
            for (int i = 0; i < 8; ++i) {
                int idx = i * NTH + tid;
                int r = idx >> 6, c = idx & 63;
                v4[r * VROW4 + c] =
                    x4[(size_t)(gb * BPG + r) * (T * 64) + (size_t)(t + 1) * 64 + c];
            }
        }
        if (t > 0) {  // y-partials for step t-1 from v.h = h_t (staggered, conflict-free)
            const float* hrow = v + bloc * VROW + D;
            const float* dwrow = dwT + cgp * U + uloc * 64;
            float partial = 0.f;
#pragma unroll 8
            for (int j = 0; j < 64; ++j) {
                int jj = (j + uloc * 8) & 63;
                partial = fmaf(hrow[uloc * 64 + jj], dwrow[jj], partial);
            }
            ybuf[bloc * 8 + uloc] = partial;
        }
        __syncthreads();   // #2: x staged, ybuf ready

        if (t + 1 < T) {   // xacc for step t+1 (t+1 > 0 -> corrected bias)
            xacc = biasr4[512 + u];
            gemm_range<64>(xacc, vrow4, Wr4 + u);
        }
        if (t > 0 && uloc == 0) {
            float yv = denseB[cgp];
#pragma unroll
            for (int q = 0; q < 8; ++q) yv += ybuf[bloc * 8 + q];
            out[(size_t)b * (T * OUTD) + (size_t)(t - 1) * OUTD + cgp] = yv;
        }

        if (tid == 0) barrier_wait(sync, (unsigned)t);
        __syncthreads();   // #3: h_{t+1} globally visible

        // ---- stage h_{t+1} into v.h via coherence-point loads (sc1) ----
        {
            const f32x4* hb4 = (const f32x4*)hnb;
#pragma unroll
            for (int half = 0; half < 2; ++half) {
                f32x4 tmp[8];
#pragma unroll
                for (int i = 0; i < 8; ++i) {
                    int idx = (half * 8 + i) * NTH + tid;   // [0, 4096)
                    int r = idx >> 7, c = idx & 127;
                    const f32x4* ap = hb4 + (size_t)(gb * BPG + r) * 128 + c;
                    asm volatile("global_load_dwordx4 %0, %1, off sc0 sc1"
                                 : "=v"(tmp[i]) : "v"(ap));
                }
                asm volatile("s_waitcnt vmcnt(0)" ::: "memory");
#pragma unroll
                for (int i = 0; i < 8; ++i) {
                    int idx = (half * 8 + i) * NTH + tid;
                    int r = idx >> 7, c = idx & 127;
                    v4[r * VROW4 + 64 + c] = tmp[i];
                }
            }
        }
        __syncthreads();   // #4: v.h = h_{t+1} ready for next iteration
    }

    // ---- epilogue: y for step T-1 from v.h = h_T ----
    {
        const float* hrow = v + bloc * VROW + D;
        const float* dwrow = dwT + cgp * U + uloc * 64;
        float partial = 0.f;
#pragma unroll 8
        for (int j = 0; j < 64; ++j) {
            int jj = (j + uloc * 8) & 63;
            partial = fmaf(hrow[uloc * 64 + jj], dwrow[jj], partial);
        }
        ybuf[bloc * 8 + uloc] = partial;
    }
    __syncthreads();
    if (uloc == 0) {
        float yv = denseB[cgp];
#pragma unroll
        for (int q = 0; q < 8; ++q) yv += ybuf[bloc * 8 + q];
        out[(size_t)b * (T * OUTD) + (size_t)(T - 1) * OUTD + cgp] = yv;
    }
}

extern "C" void kernel_launch(void* const* d_in, const int* in_sizes, int n_in,
                              void* d_out, int out_size, void* d_ws, size_t ws_size,
                              hipStream_t stream) {
    const float* x = (const float*)d_in[0];
    const float* kernelW = (const float*)d_in[1];
    const float* recW = (const float*)d_in[2];
    const float* bias = (const float*)d_in[3];
    const float* denseW = (const float*)d_in[4];
    const float* denseB = (const float*)d_in[5];
    float* ws = (float*)d_ws;
    float* Wr = ws + WR_OFF;
    float* biasr = ws + BIASR_OFF;
    float* dwT = ws + DWT_OFF;
    float* h0 = ws + H_OFF;
    float* h1 = ws + H_OFF + H_SZ;
    unsigned* sync = (unsigned*)(ws + SYNC_OFF);
    float* out = (float*)d_out;

    prep_wr<<<(KTOT * NG) / 256, 256, 0, stream>>>(kernelW, recW, denseW, Wr);
    prep_misc<<<(OUTD * U) / 256, 256, 0, stream>>>(kernelW, bias, denseW, denseB, biasr, dwT);
    prep_zero<<<(2 * (int)H_SZ) / 256, 256, 0, stream>>>(h0, sync);

    size_t smem = (size_t)(BPG * VROW + BPG * 8) * sizeof(float);  // ~99.8 KB
    hipFuncSetAttribute(reinterpret_cast<const void*>(lstm_seq),
                        hipFuncAttributeMaxDynamicSharedMemorySize, (int)smem);

    void* args[] = {(void*)&x, (void*)&Wr, (void*)&biasr, (void*)&dwT, (void*)&denseB,
                    (void*)&h0, (void*)&h1, (void*)&out, (void*)&sync};
    hipLaunchCooperativeKernel(reinterpret_cast<void*>(lstm_seq),
                               dim3(NWG), dim3(NTH), args, (unsigned)smem, stream);
}